// Round 10
// baseline (479.704 us; speedup 1.0000x reference)
//
#include <hip/hip_runtime.h>
#include <hip/hip_bf16.h>
#include <stdint.h>

// GAT forward, N=8192, IN=256, OUT=128. Inputs fp32 (adj int32), output fp32.
// softmax_j(a1_i + a2_j | adj) == adj_ij*exp(a2_j)/sum_j adj_ij*exp(a2_j)  (a1 cancels)
// -> out = (adj @ (w*h)) / (adj @ w).
// k_agg v7: 1024 blocks (256 rowsets x split-K 4), 12 waves/CU, barrier-free
// phases. Phase 1: ballot-pack 32 adj rows x 2048 cols -> 8 KB LDS bitmask
// (1 coalesced load + ~5 VALU per 64 cols, 8 loads in flight). Phase 2: A from
// LDS bitmask (broadcast ds_read_b32 + expand), B prefetched from L2-resident
// whT. LDS-reduce across 4 waves -> 4.7M atomicAdds -> k_epi divide.

typedef __attribute__((ext_vector_type(8))) short short8;
typedef __attribute__((ext_vector_type(4))) float float4v;

static __device__ __forceinline__ unsigned short f2bf(float f) {
    union { float f; uint32_t i; } v; v.f = f;
    uint32_t r = v.i + 0x7FFFu + ((v.i >> 16) & 1u);
    return (unsigned short)(r >> 16);
}

// expand low 8 bits of t -> 8 packed bf16 {0.0, 1.0}
static __device__ __forceinline__ short8 expand8(uint32_t t) {
    union { uint32_t u[4]; short8 s; } v;
    #pragma unroll
    for (int p = 0; p < 4; p++) {
        uint32_t q = t >> (2 * p);
        v.u[p] = (q & 1u) * 0x3F80u | (q & 2u) * 0x1FC00000u;
    }
    return v.s;
}

// ---- WT[n][k] = bf16(W[k][n]) : 128x256 k-major ----
__global__ void k_transpose_w(const float* __restrict__ W, unsigned short* __restrict__ WT) {
    __shared__ unsigned short tile[32][33];
    int tx = threadIdx.x & 31, ty = threadIdx.x >> 5;
    int n0 = blockIdx.x * 32, k0 = blockIdx.y * 32;
    for (int i = 0; i < 4; i++)
        tile[ty + 8 * i][tx] = f2bf(W[(k0 + ty + 8 * i) * 128 + n0 + tx]);
    __syncthreads();
    for (int i = 0; i < 4; i++)
        WT[(size_t)(n0 + ty + 8 * i) * 256 + k0 + tx] = tile[tx][ty + 8 * i];
}

// ---- fused: h = F@W+b (MFMA) -> w = exp(h.a2w+a2b) -> whT rows 0..128 ----
__global__ __launch_bounds__(256) void k_h_fused(const float* __restrict__ F,
                                                 const unsigned short* __restrict__ WT,
                                                 const float* __restrict__ bvec,
                                                 const float* __restrict__ a2w,
                                                 const float* __restrict__ a2b,
                                                 unsigned short* __restrict__ whT) {
    __shared__ __align__(16) unsigned short As[64 * 72];
    __shared__ __align__(16) unsigned short Bs[128 * 72];
    __shared__ __align__(16) unsigned short T[129 * 72];   // [col][row_local]
    __shared__ float bs[128], aw[128], ab_s;

    int t = threadIdx.x, lane = t & 63, wave = t >> 6;
    int rb = blockIdx.x * 64;
    if (t < 128) { bs[t] = bvec[t]; aw[t] = a2w[t]; }
    if (t == 0) ab_s = a2b[0];

    float4v acc[8];
    for (int c = 0; c < 8; c++) acc[c] = (float4v)0.0f;

    for (int kt = 0; kt < 4; kt++) {
        int k0 = kt * 64;
        for (int i = 0; i < 2; i++) {                       // A: 64x64 fp32 -> bf16
            int flat = t + 256 * i, row = flat >> 3, part = flat & 7;
            const float* fp = F + (size_t)(rb + row) * 256 + k0 + part * 8;
            float4 v0 = *reinterpret_cast<const float4*>(fp);
            float4 v1 = *reinterpret_cast<const float4*>(fp + 4);
            uint4 v;
            v.x = f2bf(v0.x) | ((uint32_t)f2bf(v0.y) << 16);
            v.y = f2bf(v0.z) | ((uint32_t)f2bf(v0.w) << 16);
            v.z = f2bf(v1.x) | ((uint32_t)f2bf(v1.y) << 16);
            v.w = f2bf(v1.z) | ((uint32_t)f2bf(v1.w) << 16);
            *reinterpret_cast<uint4*>(&As[row * 72 + part * 8]) = v;
        }
        for (int i = 0; i < 4; i++) {                       // B: 128x64 bf16 k-major
            int flat = t + 256 * i, n = flat >> 3, part = flat & 7;
            *reinterpret_cast<uint4*>(&Bs[n * 72 + part * 8]) =
                *reinterpret_cast<const uint4*>(WT + (size_t)n * 256 + k0 + part * 8);
        }
        __syncthreads();
        int m = lane & 15, kq = lane >> 4;
        for (int ks = 0; ks < 2; ks++) {
            short8 af = *reinterpret_cast<const short8*>(&As[(wave * 16 + m) * 72 + ks * 32 + kq * 8]);
            for (int c = 0; c < 8; c++) {
                short8 bfr = *reinterpret_cast<const short8*>(&Bs[(c * 16 + m) * 72 + ks * 32 + kq * 8]);
                acc[c] = __builtin_amdgcn_mfma_f32_16x16x32_bf16(af, bfr, acc[c], 0, 0, 0);
            }
        }
        __syncthreads();
    }

    int m = lane & 15, kq = lane >> 4;
    float hv[8][4], part[4];
    for (int r = 0; r < 4; r++) part[r] = 0.0f;
    for (int c = 0; c < 8; c++) {
        float bb = bs[c * 16 + m], a = aw[c * 16 + m];
        for (int r = 0; r < 4; r++) { hv[c][r] = acc[c][r] + bb; part[r] += hv[c][r] * a; }
    }
    for (int off = 1; off < 16; off <<= 1)
        for (int r = 0; r < 4; r++) part[r] += __shfl_xor(part[r], off, 64);
    float wr[4];
    for (int r = 0; r < 4; r++) {
        float e = fminf(fmaxf(part[r] + ab_s, -60.0f), 60.0f);
        wr[r] = expf(e);
    }
    int rl = wave * 16 + kq * 4;
    for (int c = 0; c < 8; c++)
        for (int r = 0; r < 4; r++)
            T[(c * 16 + m) * 72 + rl + r] = f2bf(hv[c][r] * wr[r]);
    if (m == 0)
        for (int r = 0; r < 4; r++)
            T[128 * 72 + rl + r] = f2bf(wr[r]);
    __syncthreads();

    for (int i = 0; i < 5; i++) {                           // 129 rows x 64 shorts
        int flat = t + 256 * i;
        if (flat < 1032) {
            int row = flat >> 3, part = flat & 7;
            *reinterpret_cast<uint4*>(whT + (size_t)row * 8192 + rb + part * 8) =
                *reinterpret_cast<const uint4*>(&T[row * 72 + part * 8]);
        }
    }
}

// ---- KMAIN: Cws[8192][144] += adj(32 rows) @ wh(K window 2048) ----
#define BM_STRIDE 65    // words/row: rows map to distinct banks, kq-group broadcasts
__global__ __launch_bounds__(256, 3) void k_agg(const int* __restrict__ adj,
                                                const unsigned short* __restrict__ whT,
                                                float* __restrict__ Cws) {
    __shared__ uint32_t bm[32 * BM_STRIDE];    //  8,320 B (32 rows x 2048 bits)
    __shared__ float red[32][148];             // 18,944 B
    int t = threadIdx.x, lane = t & 63, wave = t >> 6;   // 4 waves
    int m = lane & 15, kq = lane >> 4;
    int rowset = blockIdx.x & 255, ksplit = blockIdx.x >> 8;
    int rb = rowset * 32;
    int kbase = ksplit * 2048;

    // ---- phase 1: ballot-pack 32 rows x 2048 cols of adj into LDS bitmask ----
    {
        const int* base = adj + (size_t)(rb + wave * 8) * 8192 + kbase + lane;
        #pragma unroll 1
        for (int it = 0; it < 32; ++it) {
            int v[8];
            #pragma unroll
            for (int r8 = 0; r8 < 8; r8++)
                v[r8] = base[(size_t)r8 * 8192 + it * 64];
            #pragma unroll
            for (int r8 = 0; r8 < 8; r8++) {
                unsigned long long b = __ballot(v[r8] & 1);
                if (lane == 0) {
                    bm[(wave * 8 + r8) * BM_STRIDE + 2 * it]     = (uint32_t)b;
                    bm[(wave * 8 + r8) * BM_STRIDE + 2 * it + 1] = (uint32_t)(b >> 32);
                }
            }
        }
    }
    __syncthreads();

    // ---- phase 2: K-loop, wave covers K in [kbase+wave*512, +512), 16 iters ----
    float4v acc[2][9];
    #pragma unroll
    for (int s = 0; s < 2; s++)
        for (int c = 0; c < 9; c++) acc[s][c] = (float4v)0.0f;

    const uint32_t* bm0 = &bm[m * BM_STRIDE + wave * 16];
    const uint32_t* bm1 = &bm[(m + 16) * BM_STRIDE + wave * 16];
    const unsigned short* bp = whT + (size_t)m * 8192 + kbase + wave * 512 + kq * 8;
    int sh = kq * 8;

    short8 nb[9];
    #pragma unroll
    for (int c = 0; c < 9; c++)
        nb[c] = *reinterpret_cast<const short8*>(bp + (size_t)c * 131072);

    #pragma unroll 1
    for (int it = 0; it < 16; ++it) {
        short8 bv[9];
        #pragma unroll
        for (int c = 0; c < 9; c++) bv[c] = nb[c];
        int nk = (it < 15 ? it + 1 : 15) * 32;
        #pragma unroll
        for (int c = 0; c < 9; c++)
            nb[c] = *reinterpret_cast<const short8*>(bp + nk + (size_t)c * 131072);

        short8 af0 = expand8(bm0[it] >> sh);
        short8 af1 = expand8(bm1[it] >> sh);
        #pragma unroll
        for (int c = 0; c < 9; c++) {
            acc[0][c] = __builtin_amdgcn_mfma_f32_16x16x32_bf16(af0, bv[c], acc[0][c], 0, 0, 0);
            acc[1][c] = __builtin_amdgcn_mfma_f32_16x16x32_bf16(af1, bv[c], acc[1][c], 0, 0, 0);
        }
    }

    // ---- LDS reduction across the 4 waves ----
    for (int i = t; i < 32 * 148; i += 256)
        (&red[0][0])[i] = 0.0f;
    __syncthreads();
    for (int w = 0; w < 4; w++) {
        if (wave == w) {
            #pragma unroll
            for (int s = 0; s < 2; s++)
                for (int c = 0; c < 9; c++)
                    for (int rr = 0; rr < 4; rr++)
                        red[s * 16 + kq * 4 + rr][c * 16 + m] += acc[s][c][rr];
        }
        __syncthreads();
    }

    // ---- one atomicAdd per output elem per block (split-K=4 contributions) ----
    for (int i = t; i < 32 * 144; i += 256) {
        int r = i / 144, c = i - r * 144;
        atomicAdd(&Cws[(size_t)(rb + r) * 144 + c], red[r][c]);
    }
}

// ---- out[j][c] = fp32: C[j][c] / C[j][128] ----
__global__ void k_epi(const float* __restrict__ C, float* __restrict__ out) {
    int flat = blockIdx.x * 256 + threadIdx.x;   // 8192*32
    int j = flat >> 5, c4 = (flat & 31) * 4;
    float4 v = *reinterpret_cast<const float4*>(C + (size_t)j * 144 + c4);
    float rden = 1.0f / C[(size_t)j * 144 + 128];
    float4 o;
    o.x = v.x * rden; o.y = v.y * rden; o.z = v.z * rden; o.w = v.w * rden;
    *reinterpret_cast<float4*>(out + (size_t)j * 128 + c4) = o;
}

extern "C" void kernel_launch(void* const* d_in, const int* in_sizes, int n_in,
                              void* d_out, int out_size, void* d_ws, size_t ws_size,
                              hipStream_t stream) {
    const float* F   = (const float*)d_in[0];     // [8192][256]
    const int*   adj = (const int*)d_in[1];       // [8192][8192] 0/1
    const float* W   = (const float*)d_in[2];     // [256][128]
    const float* bv  = (const float*)d_in[3];     // [128]
    const float* a2w = (const float*)d_in[6];     // [128]  (a1 cancels; d_in[4],[5] unused)
    const float* a2b = (const float*)d_in[7];     // [1]
    float* out = (float*)d_out;                   // [8192][128]

    char* ws = (char*)d_ws;
    unsigned short* whT = (unsigned short*)(ws);            // 2,359,296 B (144 x 8192 bf16)
    float*          Cws = (float*)(ws + 2359296);           // 4,718,592 B
    unsigned short* WT  = (unsigned short*)(ws + 7077888);  //    65,536 B  (total 7.14 MB, R5-proven)

    k_transpose_w<<<dim3(4, 8), 256, 0, stream>>>(W, WT);
    k_h_fused<<<128, 256, 0, stream>>>(F, WT, bv, a2w, a2b, whT);
    hipMemsetAsync(Cws, 0, (size_t)8192 * 144 * sizeof(float), stream);
    k_agg<<<1024, 256, 0, stream>>>(adj, whT, Cws);
    k_epi<<<1024, 256, 0, stream>>>(Cws, out);
}

// Round 11
// 465.576 us; speedup vs baseline: 1.0303x; 1.0303x over previous
//
#include <hip/hip_runtime.h>
#include <hip/hip_bf16.h>
#include <stdint.h>

// GAT forward, N=8192, IN=256, OUT=128. Inputs fp32 (adj int32), output fp32.
// softmax_j(a1_i + a2_j | adj) == adj_ij*exp(a2_j)/sum_j adj_ij*exp(a2_j)  (a1 cancels)
// -> out = (adj @ (w*h)) / (adj @ w).
// k_agg v8 = R10 with ONE change: phase-1 reads adj row-at-a-time in sequential
// 8 KB runs (4 groups x 8 outstanding 256B loads) instead of round-robining 8
// rows in 256 B steps. Theory: R5-R10's ~175-200us wall is DRAM page thrash
// from ~4000 interleaved small-step streams; sequential runs restore page
// locality. Everything else (phase 2, reduce, atomics, epi) identical to R10.

typedef __attribute__((ext_vector_type(8))) short short8;
typedef __attribute__((ext_vector_type(4))) float float4v;

static __device__ __forceinline__ unsigned short f2bf(float f) {
    union { float f; uint32_t i; } v; v.f = f;
    uint32_t r = v.i + 0x7FFFu + ((v.i >> 16) & 1u);
    return (unsigned short)(r >> 16);
}

// expand low 8 bits of t -> 8 packed bf16 {0.0, 1.0}
static __device__ __forceinline__ short8 expand8(uint32_t t) {
    union { uint32_t u[4]; short8 s; } v;
    #pragma unroll
    for (int p = 0; p < 4; p++) {
        uint32_t q = t >> (2 * p);
        v.u[p] = (q & 1u) * 0x3F80u | (q & 2u) * 0x1FC00000u;
    }
    return v.s;
}

// ---- WT[n][k] = bf16(W[k][n]) : 128x256 k-major ----
__global__ void k_transpose_w(const float* __restrict__ W, unsigned short* __restrict__ WT) {
    __shared__ unsigned short tile[32][33];
    int tx = threadIdx.x & 31, ty = threadIdx.x >> 5;
    int n0 = blockIdx.x * 32, k0 = blockIdx.y * 32;
    for (int i = 0; i < 4; i++)
        tile[ty + 8 * i][tx] = f2bf(W[(k0 + ty + 8 * i) * 128 + n0 + tx]);
    __syncthreads();
    for (int i = 0; i < 4; i++)
        WT[(size_t)(n0 + ty + 8 * i) * 256 + k0 + tx] = tile[tx][ty + 8 * i];
}

// ---- fused: h = F@W+b (MFMA) -> w = exp(h.a2w+a2b) -> whT rows 0..128 ----
__global__ __launch_bounds__(256) void k_h_fused(const float* __restrict__ F,
                                                 const unsigned short* __restrict__ WT,
                                                 const float* __restrict__ bvec,
                                                 const float* __restrict__ a2w,
                                                 const float* __restrict__ a2b,
                                                 unsigned short* __restrict__ whT) {
    __shared__ __align__(16) unsigned short As[64 * 72];
    __shared__ __align__(16) unsigned short Bs[128 * 72];
    __shared__ __align__(16) unsigned short T[129 * 72];   // [col][row_local]
    __shared__ float bs[128], aw[128], ab_s;

    int t = threadIdx.x, lane = t & 63, wave = t >> 6;
    int rb = blockIdx.x * 64;
    if (t < 128) { bs[t] = bvec[t]; aw[t] = a2w[t]; }
    if (t == 0) ab_s = a2b[0];

    float4v acc[8];
    for (int c = 0; c < 8; c++) acc[c] = (float4v)0.0f;

    for (int kt = 0; kt < 4; kt++) {
        int k0 = kt * 64;
        for (int i = 0; i < 2; i++) {                       // A: 64x64 fp32 -> bf16
            int flat = t + 256 * i, row = flat >> 3, part = flat & 7;
            const float* fp = F + (size_t)(rb + row) * 256 + k0 + part * 8;
            float4 v0 = *reinterpret_cast<const float4*>(fp);
            float4 v1 = *reinterpret_cast<const float4*>(fp + 4);
            uint4 v;
            v.x = f2bf(v0.x) | ((uint32_t)f2bf(v0.y) << 16);
            v.y = f2bf(v0.z) | ((uint32_t)f2bf(v0.w) << 16);
            v.z = f2bf(v1.x) | ((uint32_t)f2bf(v1.y) << 16);
            v.w = f2bf(v1.z) | ((uint32_t)f2bf(v1.w) << 16);
            *reinterpret_cast<uint4*>(&As[row * 72 + part * 8]) = v;
        }
        for (int i = 0; i < 4; i++) {                       // B: 128x64 bf16 k-major
            int flat = t + 256 * i, n = flat >> 3, part = flat & 7;
            *reinterpret_cast<uint4*>(&Bs[n * 72 + part * 8]) =
                *reinterpret_cast<const uint4*>(WT + (size_t)n * 256 + k0 + part * 8);
        }
        __syncthreads();
        int m = lane & 15, kq = lane >> 4;
        for (int ks = 0; ks < 2; ks++) {
            short8 af = *reinterpret_cast<const short8*>(&As[(wave * 16 + m) * 72 + ks * 32 + kq * 8]);
            for (int c = 0; c < 8; c++) {
                short8 bfr = *reinterpret_cast<const short8*>(&Bs[(c * 16 + m) * 72 + ks * 32 + kq * 8]);
                acc[c] = __builtin_amdgcn_mfma_f32_16x16x32_bf16(af, bfr, acc[c], 0, 0, 0);
            }
        }
        __syncthreads();
    }

    int m = lane & 15, kq = lane >> 4;
    float hv[8][4], part[4];
    for (int r = 0; r < 4; r++) part[r] = 0.0f;
    for (int c = 0; c < 8; c++) {
        float bb = bs[c * 16 + m], a = aw[c * 16 + m];
        for (int r = 0; r < 4; r++) { hv[c][r] = acc[c][r] + bb; part[r] += hv[c][r] * a; }
    }
    for (int off = 1; off < 16; off <<= 1)
        for (int r = 0; r < 4; r++) part[r] += __shfl_xor(part[r], off, 64);
    float wr[4];
    for (int r = 0; r < 4; r++) {
        float e = fminf(fmaxf(part[r] + ab_s, -60.0f), 60.0f);
        wr[r] = expf(e);
    }
    int rl = wave * 16 + kq * 4;
    for (int c = 0; c < 8; c++)
        for (int r = 0; r < 4; r++)
            T[(c * 16 + m) * 72 + rl + r] = f2bf(hv[c][r] * wr[r]);
    if (m == 0)
        for (int r = 0; r < 4; r++)
            T[128 * 72 + rl + r] = f2bf(wr[r]);
    __syncthreads();

    for (int i = 0; i < 5; i++) {                           // 129 rows x 64 shorts
        int flat = t + 256 * i;
        if (flat < 1032) {
            int row = flat >> 3, part = flat & 7;
            *reinterpret_cast<uint4*>(whT + (size_t)row * 8192 + rb + part * 8) =
                *reinterpret_cast<const uint4*>(&T[row * 72 + part * 8]);
        }
    }
}

// ---- KMAIN: Cws[8192][144] += adj(32 rows) @ wh(K window 2048) ----
#define BM_STRIDE 65    // words/row: rows map to distinct banks, kq-group broadcasts
__global__ __launch_bounds__(256, 3) void k_agg(const int* __restrict__ adj,
                                                const unsigned short* __restrict__ whT,
                                                float* __restrict__ Cws) {
    __shared__ uint32_t bm[32 * BM_STRIDE];    //  8,320 B (32 rows x 2048 bits)
    __shared__ float red[32][148];             // 18,944 B
    int t = threadIdx.x, lane = t & 63, wave = t >> 6;   // 4 waves
    int m = lane & 15, kq = lane >> 4;
    int rowset = blockIdx.x & 255, ksplit = blockIdx.x >> 8;
    int rb = rowset * 32;
    int kbase = ksplit * 2048;

    // ---- phase 1 (v8): row-at-a-time sequential 8 KB runs, ballot-pack ----
    {
        #pragma unroll 1
        for (int r8 = 0; r8 < 8; r8++) {
            const int* rowp = adj + (size_t)(rb + wave * 8 + r8) * 8192 + kbase + lane;
            uint32_t* dst = &bm[(wave * 8 + r8) * BM_STRIDE];
            #pragma unroll 1
            for (int g = 0; g < 4; g++) {
                int v[8];
                #pragma unroll
                for (int j = 0; j < 8; j++)
                    v[j] = rowp[g * 512 + j * 64];          // 8 x 256B, contiguous 2 KB
                #pragma unroll
                for (int j = 0; j < 8; j++) {
                    unsigned long long b = __ballot(v[j] & 1);
                    if (lane == 0) {
                        dst[g * 16 + 2 * j]     = (uint32_t)b;
                        dst[g * 16 + 2 * j + 1] = (uint32_t)(b >> 32);
                    }
                }
            }
        }
    }
    __syncthreads();

    // ---- phase 2: K-loop, wave covers K in [kbase+wave*512, +512), 16 iters ----
    float4v acc[2][9];
    #pragma unroll
    for (int s = 0; s < 2; s++)
        for (int c = 0; c < 9; c++) acc[s][c] = (float4v)0.0f;

    const uint32_t* bm0 = &bm[m * BM_STRIDE + wave * 16];
    const uint32_t* bm1 = &bm[(m + 16) * BM_STRIDE + wave * 16];
    const unsigned short* bp = whT + (size_t)m * 8192 + kbase + wave * 512 + kq * 8;
    int sh = kq * 8;

    short8 nb[9];
    #pragma unroll
    for (int c = 0; c < 9; c++)
        nb[c] = *reinterpret_cast<const short8*>(bp + (size_t)c * 131072);

    #pragma unroll 1
    for (int it = 0; it < 16; ++it) {
        short8 bv[9];
        #pragma unroll
        for (int c = 0; c < 9; c++) bv[c] = nb[c];
        int nk = (it < 15 ? it + 1 : 15) * 32;
        #pragma unroll
        for (int c = 0; c < 9; c++)
            nb[c] = *reinterpret_cast<const short8*>(bp + nk + (size_t)c * 131072);

        short8 af0 = expand8(bm0[it] >> sh);
        short8 af1 = expand8(bm1[it] >> sh);
        #pragma unroll
        for (int c = 0; c < 9; c++) {
            acc[0][c] = __builtin_amdgcn_mfma_f32_16x16x32_bf16(af0, bv[c], acc[0][c], 0, 0, 0);
            acc[1][c] = __builtin_amdgcn_mfma_f32_16x16x32_bf16(af1, bv[c], acc[1][c], 0, 0, 0);
        }
    }

    // ---- LDS reduction across the 4 waves ----
    for (int i = t; i < 32 * 148; i += 256)
        (&red[0][0])[i] = 0.0f;
    __syncthreads();
    for (int w = 0; w < 4; w++) {
        if (wave == w) {
            #pragma unroll
            for (int s = 0; s < 2; s++)
                for (int c = 0; c < 9; c++)
                    for (int rr = 0; rr < 4; rr++)
                        red[s * 16 + kq * 4 + rr][c * 16 + m] += acc[s][c][rr];
        }
        __syncthreads();
    }

    // ---- one atomicAdd per output elem per block (split-K=4 contributions) ----
    for (int i = t; i < 32 * 144; i += 256) {
        int r = i / 144, c = i - r * 144;
        atomicAdd(&Cws[(size_t)(rb + r) * 144 + c], red[r][c]);
    }
}

// ---- out[j][c] = fp32: C[j][c] / C[j][128] ----
__global__ void k_epi(const float* __restrict__ C, float* __restrict__ out) {
    int flat = blockIdx.x * 256 + threadIdx.x;   // 8192*32
    int j = flat >> 5, c4 = (flat & 31) * 4;
    float4 v = *reinterpret_cast<const float4*>(C + (size_t)j * 144 + c4);
    float rden = 1.0f / C[(size_t)j * 144 + 128];
    float4 o;
    o.x = v.x * rden; o.y = v.y * rden; o.z = v.z * rden; o.w = v.w * rden;
    *reinterpret_cast<float4*>(out + (size_t)j * 128 + c4) = o;
}

extern "C" void kernel_launch(void* const* d_in, const int* in_sizes, int n_in,
                              void* d_out, int out_size, void* d_ws, size_t ws_size,
                              hipStream_t stream) {
    const float* F   = (const float*)d_in[0];     // [8192][256]
    const int*   adj = (const int*)d_in[1];       // [8192][8192] 0/1
    const float* W   = (const float*)d_in[2];     // [256][128]
    const float* bv  = (const float*)d_in[3];     // [128]
    const float* a2w = (const float*)d_in[6];     // [128]  (a1 cancels; d_in[4],[5] unused)
    const float* a2b = (const float*)d_in[7];     // [1]
    float* out = (float*)d_out;                   // [8192][128]

    char* ws = (char*)d_ws;
    unsigned short* whT = (unsigned short*)(ws);            // 2,359,296 B (144 x 8192 bf16)
    float*          Cws = (float*)(ws + 2359296);           // 4,718,592 B
    unsigned short* WT  = (unsigned short*)(ws + 7077888);  //    65,536 B  (total 7.14 MB, proven)

    k_transpose_w<<<dim3(4, 8), 256, 0, stream>>>(W, WT);
    k_h_fused<<<128, 256, 0, stream>>>(F, WT, bv, a2w, a2b, whT);
    hipMemsetAsync(Cws, 0, (size_t)8192 * 144 * sizeof(float), stream);
    k_agg<<<1024, 256, 0, stream>>>(adj, whT, Cws);
    k_epi<<<1024, 256, 0, stream>>>(Cws, out);
}